// Round 3
// baseline (15368.243 us; speedup 1.0000x reference)
//
#include <hip/hip_runtime.h>

// Tacotron-2 style decoder, B=16, T=256, DEC=1024, ENC=256, MEL=80, ATT=128.
// R10: R9's async direct-to-LDS overlap x R8's cached-coherence model.
//  - R9 post-mortem: aux=17 glls bypassed L2 -> every WG pulled its own copy of
//    the 144KB broadcast state from the fabric: FETCH 46.6MB/iter @871GB/s =
//    53.5us = the whole iteration. R8 proved {sc0sc1 producer stores + ONE
//    agent-acquire fence per iter (L2 inv) + plain cached consumer loads} is
//    correct and cheap (1.2MB/iter FETCH: one L2 refill per XCD, 31 WGs hit).
//  - R10: all global_load_lds -> aux=0 (L2-cached); acquire fence in gridbar;
//    attn/R consumer reads -> plain pipelined loads (no serialized cld RTs).
//  - wfb LDS round-trip deleted: WF[r][ll] is produced and consumed by the
//    SAME thread -> registers (removes 16-way-conflict LDS traffic + barrier).
//  - attn part B made load-free (qpm = qp2+pm precomputed pre-issue), so the
//    glls staging stays in flight across it (lgkm-only barriers between).
//  - Race fix: LSTM1's REDOFF reduce block overlaps x rows 14/15; added a
//    bar_lgkm between compute reads and reduce writes.
//  - Producer stores stay sc0sc1 (write-through to L3); barrier flags sc0sc1;
//    c1/c2 in registers; pipeline { attn(t) || R(t-1) || L1(t-2) || L2(t-3) }.

namespace {

constexpr int TT = 256, BB = 16, LL = 256, MELD = 80, FILTD = 32, KC = 31;
constexpr int P1 = 2304;      // LSTM1 xs pitch
constexpr int P2 = 2048;      // LSTM2 xs pitch
constexpr int REDOFF = 32768; // reduce block: [32768, 36864)

typedef float f32x4 __attribute__((ext_vector_type(4)));

struct Args {
  const float *enc, *spe, *mels;
  const float *Wpre1, *bpre1, *Wpre2, *bpre2, *Wsp, *bsp;
  const float *Wq, *Wm, *Wconv, *Wloc, *vatt;
  const float *Wih1, *Whh1, *bih1, *bhh1;
  const float *Wih2, *Whh2, *bih2, *bhh2;
  const float *Wmel, *bmel, *Wstop, *bstop;
  float *p, *X, *qp2, *pm2, *prevmel;
  float *h1a, *h1b, *c1, *h2a, *h2b, *c2;
  float *cum, *wexp, *uctx, *pctx, *psum, *spkvec, *spkq;
  float *W81, *b81, *tmp;
  int *slots, *epoch, *pslots, *pepoch;  // padded: slot i at [i*32]
  float *out;
};

__device__ __forceinline__ float fast_tanh(float x) {
  float ax = fabsf(x);
  float e = __expf(-2.f * ax);
  float t = (1.f - e) / (1.f + e);
  return copysignf(t, x);
}
__device__ __forceinline__ float fast_sig(float x) { return 1.f / (1.f + __expf(-x)); }

// ---- explicit-coherence primitives (barrier flags + producer stores) ----
__device__ __forceinline__ int cldi(const int* p) {
  int v;
  asm volatile("global_load_dword %0, %1, off sc0 sc1\n\ts_waitcnt vmcnt(0)"
               : "=v"(v) : "v"(p) : "memory");
  return v;
}
__device__ __forceinline__ void cst1(float* p, float v) {
  asm volatile("global_store_dword %0, %1, off sc0 sc1" :: "v"(p), "v"(v) : "memory");
}
__device__ __forceinline__ void csti(int* p, int v) {
  asm volatile("global_store_dword %0, %1, off sc0 sc1" :: "v"(p), "v"(v) : "memory");
}

// intra-WG barrier that does NOT drain vmcnt (keeps async staging in flight)
__device__ __forceinline__ void bar_lgkm() {
  asm volatile("s_waitcnt lgkmcnt(0)" ::: "memory");
  __builtin_amdgcn_s_barrier();
  __builtin_amdgcn_sched_barrier(0);
}

// async global->LDS, 16B per lane, L2-CACHED (aux=0); coherence comes from the
// per-iteration acquire fence in gridbar (R8-verified model).
__device__ __forceinline__ void glls(const float* g, float* l) {
  __builtin_amdgcn_global_load_lds((const __attribute__((address_space(1))) void*)g,
                                   (__attribute__((address_space(3))) void*)l, 16, 0, 0);
}

// Tree barrier + ONE agent-acquire (L1/L2 invalidate) per pass.
// __syncthreads() drains vmcnt -> this WG's sc0sc1 stores are at L3 before
// signal; after release the fence invalidates local caches so PLAIN loads
// (and aux=0 glls) of cross-WG data refetch fresh lines.
__device__ __forceinline__ void gridbar(int* slots, int* epoch, int target) {
  __syncthreads();
  if (blockIdx.x == 0) {
    if (threadIdx.x == 0) csti(&slots[0], target);
    while (cldi(&slots[threadIdx.x * 32]) < target) __builtin_amdgcn_s_sleep(1);
    __syncthreads();
    if (threadIdx.x == 0) csti(epoch, target);
  } else {
    if (threadIdx.x == 0) {
      csti(&slots[blockIdx.x * 32], target);
      while (cldi(epoch) < target) __builtin_amdgcn_s_sleep(8);
    }
  }
  __builtin_amdgcn_fence(__ATOMIC_ACQUIRE, "agent");
  __syncthreads();
}

__global__ void k_init(float* base, int n) {
  int i = blockIdx.x * blockDim.x + threadIdx.x;
  if (i < n) base[i] = 0.f;
}

// psum[1][b][0] = 1.0 : divisor for the zeroed step-(-1) attention weights
__global__ void k_setpsum(float* psum) {
  if (threadIdx.x < 16) psum[256 + threadIdx.x * 16] = 1.f;
}

__global__ void k_prevmel(Args a) {
  int i = blockIdx.x * blockDim.x + threadIdx.x;  // (t*16+b)*80+m
  if (i >= TT * BB * MELD) return;
  int m = i % MELD;
  int tb = i / MELD;
  int b = tb & 15, t = tb >> 4;
  a.prevmel[i] = (t == 0) ? 0.f : a.mels[(b * TT + t) * MELD + m];
}

__global__ void k_spkvec(Args a) {
  int i = blockIdx.x * blockDim.x + threadIdx.x;
  if (i >= BB * 1024) return;
  int b = i >> 10, j = i & 1023;
  const float* x = a.spe + b * 256;
  const float* w = a.Wsp + j * 256;
  float s = a.bsp[j];
  for (int k = 0; k < 256; ++k) s += x[k] * w[k];
  a.spkvec[i] = s;
}

__global__ void k_spkq(Args a) {
  int i = blockIdx.x * blockDim.x + threadIdx.x;
  if (i >= BB * 128) return;
  int b = i >> 7, q = i & 127;
  const float* x = a.spkvec + b * 1024;
  const float* w = a.Wq + q * 1024;
  float s = 0.f;
  for (int k = 0; k < 1024; ++k) s += x[k] * w[k];
  a.spkq[i] = s;
}

__global__ void k_prep81(Args a) {
  int i = blockIdx.x * blockDim.x + threadIdx.x;
  if (i < 81 * 1024) {
    int r = i >> 10, k = i & 1023;
    a.W81[i] = (r < 80) ? a.Wmel[r * 1024 + k] : a.Wstop[k];
  }
  if (i < 81) a.b81[i] = (i < 80) ? a.bmel[i] : a.bstop[0];
}

// C[M,N] = act(A[M,K] @ B[N,K]^T + bias[N]); 128x64 tile, 8x4 per thread.
__global__ __launch_bounds__(256) void k_gemm(const float* __restrict__ A,
                                              const float* __restrict__ Bm,
                                              const float* __restrict__ bias,
                                              float* __restrict__ C,
                                              int M, int N, int K, int act) {
  __shared__ __align__(16) float As[16][132];
  __shared__ __align__(16) float Bs[16][68];
  const int bm = blockIdx.y * 128, bn = blockIdx.x * 64;
  const int tid = threadIdx.x;
  const int tm = (tid >> 4) * 8, tn = (tid & 15) * 4;
  float acc[8][4] = {};
  for (int k0 = 0; k0 < K; k0 += 16) {
    for (int i = tid; i < 512; i += 256) {
      int m = i >> 2, kq = i & 3;
      float4 v = *(const float4*)(A + (size_t)(bm + m) * K + k0 + kq * 4);
      As[kq * 4 + 0][m] = v.x; As[kq * 4 + 1][m] = v.y;
      As[kq * 4 + 2][m] = v.z; As[kq * 4 + 3][m] = v.w;
    }
    {
      int m = tid >> 2, kq = tid & 3;
      float4 v = *(const float4*)(Bm + (size_t)(bn + m) * K + k0 + kq * 4);
      Bs[kq * 4 + 0][m] = v.x; Bs[kq * 4 + 1][m] = v.y;
      Bs[kq * 4 + 2][m] = v.z; Bs[kq * 4 + 3][m] = v.w;
    }
    __syncthreads();
#pragma unroll
    for (int kk = 0; kk < 16; ++kk) {
      float4 a0 = *(const float4*)&As[kk][tm];
      float4 a1 = *(const float4*)&As[kk][tm + 4];
      float4 b0 = *(const float4*)&Bs[kk][tn];
      float av[8] = {a0.x, a0.y, a0.z, a0.w, a1.x, a1.y, a1.z, a1.w};
      float bv[4] = {b0.x, b0.y, b0.z, b0.w};
#pragma unroll
      for (int i = 0; i < 8; ++i)
#pragma unroll
        for (int j = 0; j < 4; ++j) acc[i][j] += av[i] * bv[j];
    }
    __syncthreads();
  }
#pragma unroll
  for (int i = 0; i < 8; ++i)
#pragma unroll
    for (int j = 0; j < 4; ++j) {
      float v = acc[i][j];
      if (bias) v += bias[bn + tn + j];
      if (act == 1) v = fmaxf(v, 0.f);
      C[(size_t)(bm + tm + i) * N + bn + tn + j] = v;
    }
}

__global__ void k_pm_transpose(Args a) {
  int i = blockIdx.x * blockDim.x + threadIdx.x;  // dest (b*128+q)*256 + l
  if (i >= BB * 128 * LL) return;
  int l = i & 255;
  int rest = i >> 8;
  int q = rest & 127, b = rest >> 7;
  a.pm2[i] = a.X[(size_t)((b << 8) + l) * 128 + q];
}

__global__ void k_addspkq(Args a) {
  int i = blockIdx.x * blockDim.x + threadIdx.x;
  if (i >= TT * BB * 128) return;
  int q = i & 127, b = (i >> 7) & 15;
  a.qp2[i] += a.spkq[b * 128 + q];
}

// ================= persistent decoder loop =================
// iter t: attn(t) || R(t-1) || LSTM1(t-2) || LSTM2(t-3); 259 iterations.
__global__ __launch_bounds__(256, 1) void k_persist(Args a) {
  __shared__ __align__(16) float xs[16 * P1];   // 147,456 B: x staging + reduce
  __shared__ __align__(16) float asc[720];      // attn: loc0|loc1|F(16x36)|expv
  __shared__ __align__(16) float gbuf2[280];    // gate exchange [4][68]
  const int wg = blockIdx.x, tid = threadIdx.x;
  const int wv = tid >> 6, lane = tid & 63;
  const int d0 = wg * 4, kl = lane * 4;
  const int ag = tid & 15, ll = tid >> 4;

  float* loc0 = asc;
  float* loc1 = asc + 64;
  float* aF   = asc + 128;   // 16 x 36 (pitch 36: 16B-aligned rows, 2-way banks)
  float* expv = asc + 704;   // 16

  // ---- stationary LSTM weights (loaded once; spill to AGPRs, no mem traffic) --
  float4 wL1[9][4];
  float4 wL2[8][4];
#pragma unroll
  for (int q = 0; q < 4; ++q) {
    const int row = wv * 1024 + d0 + q;
    const float* rih1 = a.Wih1 + (size_t)row * 1280;
    const float* rhh1 = a.Whh1 + (size_t)row * 1024;
    const float* rih2 = a.Wih2 + (size_t)row * 1024;
    const float* rhh2 = a.Whh2 + (size_t)row * 1024;
#pragma unroll
    for (int kb = 0; kb < 9; ++kb)
      wL1[kb][q] = (kb < 5) ? *(const float4*)(rih1 + kb * 256 + kl)
                            : *(const float4*)(rhh1 + kb * 256 + kl - 1280);
#pragma unroll
    for (int kb = 0; kb < 8; ++kb)
      wL2[kb][q] = (kb < 4) ? *(const float4*)(rih2 + kb * 256 + kl)
                            : *(const float4*)(rhh2 + kb * 256 + kl - 1024);
  }
  const int row_r = wv * 1024 + d0 + (lane >> 4);
  const float bsum1 = a.bih1[row_r] + a.bhh1[row_r];
  const float bsum2 = a.bih2[row_r] + a.bhh2[row_r];

  // ---- t-invariant attention operands -> registers ----
  const int bH = wg >> 4, cH = wg & 15, l0H = cH << 4, lH = l0H + ll;
  float pmv[8], va[8];
  {
    const float* pmb = a.pm2 + (size_t)bH * 32768;
#pragma unroll
    for (int j = 0; j < 8; ++j) {
      pmv[j] = pmb[(size_t)(ag * 8 + j) * 256 + lH];
      va[j] = a.vatt[ag * 8 + j];
    }
  }
  float ev[16];
  {
    const float* eb = a.enc + (size_t)((bH << 8) + l0H) * 256 + tid;
#pragma unroll
    for (int l2 = 0; l2 < 16; ++l2) ev[l2] = eb[l2 * 256];
  }

  // LSTM cell state in registers: tid<64 owns (b=tid&15, d=d0+(tid>>4))
  float c1v = 0.f, c2v = 0.f;
  __syncthreads();

  for (int t = 0; t < 259; ++t) {
    const int cur = t & 1, prv = cur ^ 1;

    // ---------- R(s = t-1): reduce pctx -> normalized uctx (plain loads) ------
    if (wg < 16 && t >= 1 && t <= 256) {
      const int par = (t - 1) & 1, b = wg;
      float sm;
      {
        const f32x4* ps4 = (const f32x4*)(a.psum + par * 256 + b * 16);
        f32x4 p0 = ps4[0], p1 = ps4[1], p2 = ps4[2], p3 = ps4[3];
        sm = (p0[0] + p0[1] + p0[2] + p0[3]) + (p1[0] + p1[1] + p1[2] + p1[3]) +
             (p2[0] + p2[1] + p2[2] + p2[3]) + (p3[0] + p3[1] + p3[2] + p3[3]);
      }
      const float inv = 1.f / sm;
      const float* pc = a.pctx + par * 65536 + b * 4096 + tid;
      float acc = 0.f;
#pragma unroll
      for (int i = 0; i < 16; ++i) acc += pc[i * 256];
      cst1(a.uctx + par * 4096 + b * 256 + tid, acc * inv);
    }

    // ---------- attention(t), part A: all global consumes happen HERE ---------
    float qpm[8], wf[8];
    if (t < 256) {
      float sm;
      {
        const f32x4* ps4 = (const f32x4*)(a.psum + prv * 256 + bH * 16);
        f32x4 p0 = ps4[0], p1 = ps4[1], p2 = ps4[2], p3 = ps4[3];
        sm = (p0[0] + p0[1] + p0[2] + p0[3]) + (p1[0] + p1[1] + p1[2] + p1[3]) +
             (p2[0] + p2[1] + p2[2] + p2[3]) + (p3[0] + p3[1] + p3[2] + p3[3]);
      }
      const float inv_ps = 1.f / sm;
      {
        const float* qpb = a.qp2 + ((size_t)(t << 4) + bH) * 128 + ag * 8;
        float4 q0 = *(const float4*)qpb;
        float4 q1 = *(const float4*)(qpb + 4);
        qpm[0] = q0.x + pmv[0]; qpm[1] = q0.y + pmv[1];
        qpm[2] = q0.z + pmv[2]; qpm[3] = q0.w + pmv[3];
        qpm[4] = q1.x + pmv[4]; qpm[5] = q1.y + pmv[5];
        qpm[6] = q1.z + pmv[6]; qpm[7] = q1.w + pmv[7];
      }
      if (tid < 64) {
        int lp = l0H - 16 + tid;
        bool ok = (lp >= 0 && lp < LL);
        float we = 0.f, cm = 0.f;
        if (ok) {
          we = a.wexp[prv * 4096 + bH * 256 + lp];
          cm = a.cum[prv * 4096 + bH * 256 + lp];
        }
        float wn = we * inv_ps;
        loc0[tid] = wn;
        loc1[tid] = ok ? (cm + wn) : 0.f;
      }
      bar_lgkm();
      // cum(t) own slice = cumulative through step t-1
      if (tid < 16) cst1(a.cum + cur * 4096 + bH * 256 + l0H + tid, loc1[16 + tid]);
      for (int idx = tid; idx < FILTD * 16; idx += 256) {
        int fc = idx >> 4, ll2 = idx & 15;
        const float* w = a.Wconv + fc * 62;
        float s = 0.f;
#pragma unroll
        for (int k = 0; k < KC; ++k) {
          s += w[k] * loc0[ll2 + k + 1];
          s += w[31 + k] * loc1[ll2 + k + 1];
        }
        aF[ll2 * 36 + fc] = s;
      }
      bar_lgkm();
      // wf[j] = (Wloc @ F)[r][ll], r=ag*8+j — produced AND consumed by this
      // thread: keep in registers (R9's LDS round-trip was pure waste).
      {
        const float* ftr = aF + ll * 36;
        f32x4 f[8];
#pragma unroll
        for (int c4 = 0; c4 < 8; ++c4) f[c4] = *(const f32x4*)(ftr + c4 * 4);
#pragma unroll
        for (int j = 0; j < 8; ++j) {
          const float* wl = a.Wloc + (ag * 8 + j) * 32;
          float x = 0.f;
#pragma unroll
          for (int c4 = 0; c4 < 8; ++c4) {
            float4 w4 = *(const float4*)(wl + c4 * 4);
            x += w4.x * f[c4][0] + w4.y * f[c4][1] + w4.z * f[c4][2] + w4.w * f[c4][3];
          }
          wf[j] = x;
        }
      }
    }

    // ---------- LSTM1(t-2) staging: async L2-cached, 36 glls per wave --------
    if (t >= 2 && t <= 257) {
      const int s1 = t - 2;
      const float* pt = a.p + (size_t)s1 * 16384;
      const float* h1r = (s1 & 1) ? a.h1a : a.h1b;  // h1(s1-1)
      const float* uc = a.uctx + (size_t)(s1 & 1) * 4096;
#pragma unroll
      for (int k = 0; k < 16; ++k)
        glls(pt + (size_t)(tid + k * 256) * 4, xs + k * P1 + wv * 256);
#pragma unroll
      for (int k = 0; k < 4; ++k)
        glls(uc + (size_t)(tid + k * 256) * 4, xs + (k * 4 + wv) * P1 + 1024);
#pragma unroll
      for (int k = 0; k < 16; ++k)
        glls(h1r + (size_t)(tid + k * 256) * 4, xs + k * P1 + 1280 + wv * 256);
    }

    // ---------- attention(t), part B: LOAD-FREE (regs + LDS only) ------------
    if (t < 256) {
      {
        float s = 0.f;
#pragma unroll
        for (int j = 0; j < 8; ++j) s += va[j] * fast_tanh(qpm[j] + wf[j]);
        s += __shfl_down(s, 8, 16);
        s += __shfl_down(s, 4, 16);
        s += __shfl_down(s, 2, 16);
        s += __shfl_down(s, 1, 16);
        if (ag == 0) {
          float ex = __expf(s);  // |e| small -> no max-subtraction needed
          expv[ll] = ex;
          cst1(a.wexp + cur * 4096 + bH * 256 + lH, ex);
        }
      }
      bar_lgkm();  // expv visible; staging stays in flight
      if (tid == 0) {
        float s = 0.f;
#pragma unroll
        for (int i = 0; i < 16; ++i) s += expv[i];
        cst1(a.psum + cur * 256 + bH * 16 + cH, s);
      }
      {
        float sctx = 0.f;
#pragma unroll
        for (int l2 = 0; l2 < 16; ++l2) sctx += expv[l2] * ev[l2];
        cst1(a.pctx + cur * 65536 + (bH * 16 + cH) * 256 + tid, sctx);
      }
    }

    // ---------- LSTM1(t-2) compute ----------
    if (t >= 2 && t <= 257) {
      __syncthreads();  // drains vmcnt(0): staging arrived, xs visible
      float acc[4][16];
#pragma unroll
      for (int q = 0; q < 4; ++q)
#pragma unroll
        for (int b = 0; b < 16; ++b) acc[q][b] = 0.f;
#pragma unroll
      for (int kb = 0; kb < 9; ++kb) {
        const float* xb = xs + kb * 256 + kl;
#pragma unroll
        for (int b = 0; b < 16; ++b) {
          float4 x4 = *(const float4*)(xb + b * P1);
#pragma unroll
          for (int q = 0; q < 4; ++q) {
            acc[q][b] += wL1[kb][q].x * x4.x;
            acc[q][b] += wL1[kb][q].y * x4.y;
            acc[q][b] += wL1[kb][q].z * x4.z;
            acc[q][b] += wL1[kb][q].w * x4.w;
          }
        }
      }
      // collapse 64 -> 16 lane-columns
#pragma unroll
      for (int q = 0; q < 4; ++q)
#pragma unroll
        for (int b = 0; b < 16; ++b) {
          float v = acc[q][b];
          v += __shfl_xor(v, 32);
          v += __shfl_xor(v, 16);
          acc[q][b] = v;
        }
      bar_lgkm();  // RACE FIX: REDOFF overlaps x rows 14/15 — all reads first
      if (lane < 16) {
        float* rb = xs + REDOFF + wv * 1024 + lane * 64;
        const int sx = lane << 2;
#pragma unroll
        for (int q = 0; q < 4; ++q)
#pragma unroll
          for (int bg = 0; bg < 4; ++bg) {
            f32x4 v = {acc[q][bg * 4 + 0], acc[q][bg * 4 + 1],
                       acc[q][bg * 4 + 2], acc[q][bg * 4 + 3]};
            *(f32x4*)(rb + ((q * 16 + bg * 4) ^ sx)) = v;
          }
      }
    }

    // ---------- LSTM2(t-3) staging: async L2-cached, 32 glls per wave --------
    // xs[0..32768) is free (barrier above); REDOFF region disjoint.
    if (t >= 3) {
      const int s2 = t - 3;
      const float* h1s = (s2 & 1) ? a.h1b : a.h1a;  // h1(s2)
      const float* h2r = (s2 & 1) ? a.h2a : a.h2b;  // h2(s2-1)
#pragma unroll
      for (int k = 0; k < 16; ++k)
        glls(h1s + (size_t)(tid + k * 256) * 4, xs + k * P2 + wv * 256);
#pragma unroll
      for (int k = 0; k < 16; ++k)
        glls(h2r + (size_t)(tid + k * 256) * 4, xs + k * P2 + 1024 + wv * 256);
    }

    // ---------- LSTM1(t-2) finish: readback (wave-local) + gates ----------
    if (t >= 2 && t <= 257) {
      float* h1w = ((t - 2) & 1) ? a.h1b : a.h1a;  // h1(s1)
      {
        const int lo = lane & ~3, li = lane & 3;
        const float* rbase = xs + REDOFF + wv * 1024;
        float g = bsum1;
#pragma unroll
        for (int k = 0; k < 16; ++k) g += rbase[k * 64 + (lo ^ (k << 2)) + li];
        gbuf2[wv * 68 + lane] = g;  // (gate=wv, d=d0+(lane>>4), b=lane&15)
      }
      bar_lgkm();
      if (tid < 64) {
        int dd = tid >> 4, b = tid & 15, d = d0 + dd;
        float gi = gbuf2[0 * 68 + tid], gf = gbuf2[1 * 68 + tid];
        float gg = gbuf2[2 * 68 + tid], go = gbuf2[3 * 68 + tid];
        float cn = fast_sig(gf) * c1v + fast_sig(gi) * fast_tanh(gg);
        float hn = fast_sig(go) * fast_tanh(cn);
        c1v = cn;
        cst1(h1w + b * 1024 + d, hn);  // cross-WG: write-through
      }
    }

    // ---------- LSTM2(t-3) compute + finish ----------
    if (t >= 3) {
      const int s2 = t - 3;
      float* h2w = (s2 & 1) ? a.h2b : a.h2a;  // h2(s2)
      __syncthreads();  // drains vmcnt(0): LSTM2 staging arrived
      float acc[4][16];
#pragma unroll
      for (int q = 0; q < 4; ++q)
#pragma unroll
        for (int b = 0; b < 16; ++b) acc[q][b] = 0.f;
#pragma unroll
      for (int kb = 0; kb < 8; ++kb) {
        const float* xb = xs + kb * 256 + kl;
#pragma unroll
        for (int b = 0; b < 16; ++b) {
          float4 x4 = *(const float4*)(xb + b * P2);
#pragma unroll
          for (int q = 0; q < 4; ++q) {
            acc[q][b] += wL2[kb][q].x * x4.x;
            acc[q][b] += wL2[kb][q].y * x4.y;
            acc[q][b] += wL2[kb][q].z * x4.z;
            acc[q][b] += wL2[kb][q].w * x4.w;
          }
        }
      }
#pragma unroll
      for (int q = 0; q < 4; ++q)
#pragma unroll
        for (int b = 0; b < 16; ++b) {
          float v = acc[q][b];
          v += __shfl_xor(v, 32);
          v += __shfl_xor(v, 16);
          acc[q][b] = v;
        }
      // REDOFF [32768,36864) disjoint from LSTM2 x rows [0,32768) — no barrier
      if (lane < 16) {
        float* rb = xs + REDOFF + wv * 1024 + lane * 64;
        const int sx = lane << 2;
#pragma unroll
        for (int q = 0; q < 4; ++q)
#pragma unroll
          for (int bg = 0; bg < 4; ++bg) {
            f32x4 v = {acc[q][bg * 4 + 0], acc[q][bg * 4 + 1],
                       acc[q][bg * 4 + 2], acc[q][bg * 4 + 3]};
            *(f32x4*)(rb + ((q * 16 + bg * 4) ^ sx)) = v;
          }
      }
      {
        const int lo = lane & ~3, li = lane & 3;
        const float* rbase = xs + REDOFF + wv * 1024;
        float g = bsum2;
#pragma unroll
        for (int k = 0; k < 16; ++k) g += rbase[k * 64 + (lo ^ (k << 2)) + li];
        gbuf2[wv * 68 + lane] = g;
      }
      bar_lgkm();
      if (tid < 64) {
        int dd = tid >> 4, b = tid & 15, d = d0 + dd;
        float gi = gbuf2[0 * 68 + tid], gf = gbuf2[1 * 68 + tid];
        float gg = gbuf2[2 * 68 + tid], go = gbuf2[3 * 68 + tid];
        float cn = fast_sig(gf) * c2v + fast_sig(gi) * fast_tanh(gg);
        float hn = fast_sig(go) * fast_tanh(cn);
        c2v = cn;
        cst1(h2w + b * 1024 + d, hn);                // cross-WG: coherent
        a.X[(size_t)(s2 * 16 + b) * 1024 + d] = hn;  // epilogue-only: plain
      }
    }

    if (t < 258) gridbar(a.slots, a.epoch, t + 1);
  }
}

__global__ void k_finish(Args a) {
  int i = blockIdx.x * blockDim.x + threadIdx.x;  // tb*128+col
  if (i >= 4096 * 128) return;
  int col = i & 127, tb = i >> 7;
  int t = tb >> 4, b = tb & 15;
  float v = a.tmp[i];
  if (col < 80) a.out[(size_t)(b * 256 + t) * 80 + col] = v;
  else if (col == 80) a.out[327680 + b * 256 + t] = fast_sig(v);
}

}  // namespace

extern "C" void kernel_launch(void* const* d_in, const int* in_sizes, int n_in,
                              void* d_out, int out_size, void* d_ws, size_t ws_size,
                              hipStream_t stream) {
  float* ws = (float*)d_ws;
  Args a;
  a.enc = (const float*)d_in[0];
  a.spe = (const float*)d_in[1];
  a.mels = (const float*)d_in[2];
  a.Wpre1 = (const float*)d_in[3];  a.bpre1 = (const float*)d_in[4];
  a.Wpre2 = (const float*)d_in[5];  a.bpre2 = (const float*)d_in[6];
  a.Wsp = (const float*)d_in[7];    a.bsp = (const float*)d_in[8];
  a.Wq = (const float*)d_in[9];     a.Wm = (const float*)d_in[10];
  a.Wconv = (const float*)d_in[11]; a.Wloc = (const float*)d_in[12];
  a.vatt = (const float*)d_in[13];
  a.Wih1 = (const float*)d_in[14];  a.Whh1 = (const float*)d_in[15];
  a.bih1 = (const float*)d_in[16];  a.bhh1 = (const float*)d_in[17];
  a.Wih2 = (const float*)d_in[18];  a.Whh2 = (const float*)d_in[19];
  a.bih2 = (const float*)d_in[20];  a.bhh2 = (const float*)d_in[21];
  a.Wmel = (const float*)d_in[22];  a.bmel = (const float*)d_in[23];
  a.Wstop = (const float*)d_in[24]; a.bstop = (const float*)d_in[25];

  // ws layout (floats), total 10,382,016 floats ~= 41.5 MB
  a.p    = ws + 0;         // 4096x1024
  a.X    = ws + 4194304;   // prenet hidden -> pm temp -> h2_all
  a.qp2  = ws + 8388608;   // 4096x128
  a.pm2  = ws + 8912896;   // 16x128x256
  float* st = ws + 9437184;  // STATE block, 270,912 floats (zeroed each launch)
  a.h1a = st + 0;      a.h1b = st + 16384;
  a.c1  = st + 32768;
  a.h2a = st + 49152;  a.h2b = st + 65536;
  a.c2  = st + 81920;
  a.cum  = st + 98304;    // [2][16][256]
  a.wexp = st + 106496;   // [2][16][256]
  a.uctx = st + 114688;   // [2][16][256]
  a.pctx = st + 122880;   // [2][16][16][256]
  a.psum = st + 253952;   // [2][16][16]
  a.slots  = (int*)(st + 254464);  // 256 slots x 32-int pad
  a.epoch  = (int*)(st + 262656);  // 1 x 32-int pad
  a.pslots = (int*)(st + 262688);  // (unused, kept for layout)
  a.pepoch = (int*)(st + 270880);
  a.spkvec = ws + 9708096;  // 16x1024
  a.spkq   = ws + 9724480;  // 16x128
  a.W81    = ws + 9726528;  // 128x1024 (rows 81..127 unused)
  a.b81    = ws + 9857600;  // 128
  a.tmp    = ws + 9857728;  // 4096x128
  a.prevmel = a.tmp;        // prologue-only, aliases epilogue tmp
  a.out = (float*)d_out;

  k_init<<<(270912 + 255) / 256, 256, 0, stream>>>(st, 270912);
  k_setpsum<<<1, 64, 0, stream>>>(a.psum);
  k_prevmel<<<(TT * BB * MELD + 255) / 256, 256, 0, stream>>>(a);
  k_spkvec<<<(BB * 1024 + 255) / 256, 256, 0, stream>>>(a);
  k_spkq<<<(BB * 128 + 255) / 256, 256, 0, stream>>>(a);
  k_prep81<<<(81 * 1024 + 255) / 256, 256, 0, stream>>>(a);

  // prenet1 -> X (temp), prenet2 -> p
  k_gemm<<<dim3(16, 32), 256, 0, stream>>>(a.prevmel, a.Wpre1, a.bpre1, a.X, 4096, 1024, 80, 1);
  k_gemm<<<dim3(16, 32), 256, 0, stream>>>(a.X, a.Wpre2, a.bpre2, a.p, 4096, 1024, 1024, 1);
  // qp2 = p @ Wq^T (+ spk @ Wq^T)
  k_gemm<<<dim3(2, 32), 256, 0, stream>>>(a.p, a.Wq, nullptr, a.qp2, 4096, 128, 1024, 0);
  k_addspkq<<<(TT * BB * 128 + 255) / 256, 256, 0, stream>>>(a);
  // proc_mem = enc @ Wm^T -> X temp -> transpose to [b][att][l]
  k_gemm<<<dim3(2, 32), 256, 0, stream>>>(a.enc, a.Wm, nullptr, a.X, 4096, 128, 256, 0);
  k_pm_transpose<<<(BB * 128 * LL + 255) / 256, 256, 0, stream>>>(a);

  // persistent decoder: 256 WGs (1/CU), cooperative; fallback to plain launch
  {
    void* kargs[] = {(void*)&a};
    hipError_t e = hipLaunchCooperativeKernel(reinterpret_cast<const void*>(&k_persist),
                                              dim3(256), dim3(256), kargs, 0, stream);
    if (e != hipSuccess) k_persist<<<256, 256, 0, stream>>>(a);
  }

  // mel/stop projection: h2_all @ W81^T -> tmp, then scatter
  k_gemm<<<dim3(2, 32), 256, 0, stream>>>(a.X, a.W81, a.b81, a.tmp, 4096, 128, 1024, 0);
  k_finish<<<(4096 * 128 + 255) / 256, 256, 0, stream>>>(a);
}

// Round 4
// 14122.911 us; speedup vs baseline: 1.0882x; 1.0882x over previous
//
#include <hip/hip_runtime.h>

// Tacotron-2 style decoder, B=16, T=256, DEC=1024, ENC=256, MEL=80, ATT=128.
// R11: depth-32 rotating broadcast buffers -> L2 line sharing without fences.
//  - R10 post-mortem: FETCH stayed 46MB/iter (== R9) because "one fence/iter"
//    is really 256 STAGGERED full-L2 invalidates/iter: 32 WGs/XCD wipe their
//    XCD's L2 at skewed barrier times while the other 31 are mid-staging ->
//    line sharing destroyed -> still fabric-bound (46MB @ ~820GB/s = 56us).
//  - R11: h1/h2/uctx/psum become time-rotated (slot = (step+1)&31). A plain
//    L2-cached read at iter t touches lines last cached 32 iters earlier; ONE
//    agent-acquire fence every 16 iters (reuse window 30 > 16) makes a stale
//    hit impossible. 255/256 barriers carry NO invalidate -> 32 WGs/XCD share
//    each 210KB broadcast set via L2 (compulsory ~1.7MB/iter chip-wide).
//  - Producers keep sc0sc1 write-through stores (L2 never dirty for shared
//    data). Small 2-parity state (wexp/cum/pctx) reads revert to R7's proven
//    batched sc0sc1 register loads. Staging stays async glls aux=0 (R9/R10
//    structure: issue early, drain at the natural __syncthreads).
//  - Pipeline unchanged: { attn(t) || R(t-1) || LSTM1(t-2) || LSTM2(t-3) },
//    259 iters, c1/c2 in registers, attn part B load-free.

namespace {

constexpr int TT = 256, BB = 16, LL = 256, MELD = 80, FILTD = 32, KC = 31;
constexpr int P1 = 2304;      // LSTM1 xs pitch
constexpr int P2 = 2048;      // LSTM2 xs pitch
constexpr int REDOFF = 32768; // reduce block: [32768, 36864)

typedef float f32x4 __attribute__((ext_vector_type(4)));

struct Args {
  const float *enc, *spe, *mels;
  const float *Wpre1, *bpre1, *Wpre2, *bpre2, *Wsp, *bsp;
  const float *Wq, *Wm, *Wconv, *Wloc, *vatt;
  const float *Wih1, *Whh1, *bih1, *bhh1;
  const float *Wih2, *Whh2, *bih2, *bhh2;
  const float *Wmel, *bmel, *Wstop, *bstop;
  float *p, *X, *qp2, *pm2, *prevmel;
  float *cum, *wexp, *pctx, *spkvec, *spkq;
  float *h1d, *h2d, *uctxd, *psumd;  // depth-32 rotating broadcast buffers
  float *W81, *b81, *tmp;
  int *slots, *epoch;  // padded: slot i at [i*32]
  float *out;
};

__device__ __forceinline__ float fast_tanh(float x) {
  float ax = fabsf(x);
  float e = __expf(-2.f * ax);
  float t = (1.f - e) / (1.f + e);
  return copysignf(t, x);
}
__device__ __forceinline__ float fast_sig(float x) { return 1.f / (1.f + __expf(-x)); }

// ---- explicit-coherence primitives: sc0 sc1 = bypass L1/L2, L3 is PoC ----
__device__ __forceinline__ int cldi(const int* p) {
  int v;
  asm volatile("global_load_dword %0, %1, off sc0 sc1\n\ts_waitcnt vmcnt(0)"
               : "=v"(v) : "v"(p) : "memory");
  return v;
}
__device__ __forceinline__ void cst1(float* p, float v) {
  asm volatile("global_store_dword %0, %1, off sc0 sc1" :: "v"(p), "v"(v) : "memory");
}
__device__ __forceinline__ void csti(int* p, int v) {
  asm volatile("global_store_dword %0, %1, off sc0 sc1" :: "v"(p), "v"(v) : "memory");
}
// 2x dword coherent loads, ONE waitcnt
__device__ __forceinline__ void cld2(float* d0, float* d1, const float* q0,
                                     const float* q1) {
  float x, y;
  asm volatile(
      "global_load_dword %0, %2, off sc0 sc1\n\t"
      "global_load_dword %1, %3, off sc0 sc1\n\t"
      "s_waitcnt vmcnt(0)"
      : "=&v"(x), "=&v"(y) : "v"(q0), "v"(q1) : "memory");
  *d0 = x; *d1 = y;
}
// 8x dword coherent loads, ONE waitcnt
__device__ __forceinline__ void cld8d(float d[8], const float* q0, const float* q1,
                                      const float* q2, const float* q3, const float* q4,
                                      const float* q5, const float* q6, const float* q7) {
  asm volatile(
      "global_load_dword %0, %8, off sc0 sc1\n\t"
      "global_load_dword %1, %9, off sc0 sc1\n\t"
      "global_load_dword %2, %10, off sc0 sc1\n\t"
      "global_load_dword %3, %11, off sc0 sc1\n\t"
      "global_load_dword %4, %12, off sc0 sc1\n\t"
      "global_load_dword %5, %13, off sc0 sc1\n\t"
      "global_load_dword %6, %14, off sc0 sc1\n\t"
      "global_load_dword %7, %15, off sc0 sc1\n\t"
      "s_waitcnt vmcnt(0)"
      : "=&v"(d[0]), "=&v"(d[1]), "=&v"(d[2]), "=&v"(d[3]),
        "=&v"(d[4]), "=&v"(d[5]), "=&v"(d[6]), "=&v"(d[7])
      : "v"(q0), "v"(q1), "v"(q2), "v"(q3), "v"(q4), "v"(q5), "v"(q6), "v"(q7)
      : "memory");
}

// intra-WG barrier that does NOT drain vmcnt (keeps async staging in flight)
__device__ __forceinline__ void bar_lgkm() {
  asm volatile("s_waitcnt lgkmcnt(0)" ::: "memory");
  __builtin_amdgcn_s_barrier();
  __builtin_amdgcn_sched_barrier(0);
}

// async global->LDS, 16B per lane, L2-CACHED (aux=0). Safe because rotated
// buffers guarantee the line was last cached >=32 iters ago and a fence every
// 16 iters wiped it since.
__device__ __forceinline__ void glls(const float* g, float* l) {
  __builtin_amdgcn_global_load_lds((const __attribute__((address_space(1))) void*)g,
                                   (__attribute__((address_space(3))) void*)l, 16, 0, 0);
}

// Tree barrier; agent-acquire (L1/L2 invalidate) only when inv==true (every
// 16th iteration). __syncthreads() drains vmcnt -> this WG's sc0sc1 stores are
// at L3 before tid0 signals.
__device__ __forceinline__ void gridbar(int* slots, int* epoch, int target, bool inv) {
  __syncthreads();
  if (blockIdx.x == 0) {
    if (threadIdx.x == 0) csti(&slots[0], target);
    while (cldi(&slots[threadIdx.x * 32]) < target) __builtin_amdgcn_s_sleep(1);
    __syncthreads();
    if (threadIdx.x == 0) csti(epoch, target);
  } else {
    if (threadIdx.x == 0) {
      csti(&slots[blockIdx.x * 32], target);
      while (cldi(epoch) < target) __builtin_amdgcn_s_sleep(8);
    }
  }
  if (inv) __builtin_amdgcn_fence(__ATOMIC_ACQUIRE, "agent");
  __syncthreads();
}

__global__ void k_init(float* base, int n) {
  int i = blockIdx.x * blockDim.x + threadIdx.x;
  if (i < n) base[i] = 0.f;
}

// psumd slot0 [b][0] = 1.0 : divisor for the zeroed step-(-1) attention weights
__global__ void k_setpsum(float* psumd) {
  if (threadIdx.x < 16) psumd[threadIdx.x * 16] = 1.f;
}

__global__ void k_prevmel(Args a) {
  int i = blockIdx.x * blockDim.x + threadIdx.x;  // (t*16+b)*80+m
  if (i >= TT * BB * MELD) return;
  int m = i % MELD;
  int tb = i / MELD;
  int b = tb & 15, t = tb >> 4;
  a.prevmel[i] = (t == 0) ? 0.f : a.mels[(b * TT + t) * MELD + m];
}

__global__ void k_spkvec(Args a) {
  int i = blockIdx.x * blockDim.x + threadIdx.x;
  if (i >= BB * 1024) return;
  int b = i >> 10, j = i & 1023;
  const float* x = a.spe + b * 256;
  const float* w = a.Wsp + j * 256;
  float s = a.bsp[j];
  for (int k = 0; k < 256; ++k) s += x[k] * w[k];
  a.spkvec[i] = s;
}

__global__ void k_spkq(Args a) {
  int i = blockIdx.x * blockDim.x + threadIdx.x;
  if (i >= BB * 128) return;
  int b = i >> 7, q = i & 127;
  const float* x = a.spkvec + b * 1024;
  const float* w = a.Wq + q * 1024;
  float s = 0.f;
  for (int k = 0; k < 1024; ++k) s += x[k] * w[k];
  a.spkq[i] = s;
}

__global__ void k_prep81(Args a) {
  int i = blockIdx.x * blockDim.x + threadIdx.x;
  if (i < 81 * 1024) {
    int r = i >> 10, k = i & 1023;
    a.W81[i] = (r < 80) ? a.Wmel[r * 1024 + k] : a.Wstop[k];
  }
  if (i < 81) a.b81[i] = (i < 80) ? a.bmel[i] : a.bstop[0];
}

// C[M,N] = act(A[M,K] @ B[N,K]^T + bias[N]); 128x64 tile, 8x4 per thread.
__global__ __launch_bounds__(256) void k_gemm(const float* __restrict__ A,
                                              const float* __restrict__ Bm,
                                              const float* __restrict__ bias,
                                              float* __restrict__ C,
                                              int M, int N, int K, int act) {
  __shared__ __align__(16) float As[16][132];
  __shared__ __align__(16) float Bs[16][68];
  const int bm = blockIdx.y * 128, bn = blockIdx.x * 64;
  const int tid = threadIdx.x;
  const int tm = (tid >> 4) * 8, tn = (tid & 15) * 4;
  float acc[8][4] = {};
  for (int k0 = 0; k0 < K; k0 += 16) {
    for (int i = tid; i < 512; i += 256) {
      int m = i >> 2, kq = i & 3;
      float4 v = *(const float4*)(A + (size_t)(bm + m) * K + k0 + kq * 4);
      As[kq * 4 + 0][m] = v.x; As[kq * 4 + 1][m] = v.y;
      As[kq * 4 + 2][m] = v.z; As[kq * 4 + 3][m] = v.w;
    }
    {
      int m = tid >> 2, kq = tid & 3;
      float4 v = *(const float4*)(Bm + (size_t)(bn + m) * K + k0 + kq * 4);
      Bs[kq * 4 + 0][m] = v.x; Bs[kq * 4 + 1][m] = v.y;
      Bs[kq * 4 + 2][m] = v.z; Bs[kq * 4 + 3][m] = v.w;
    }
    __syncthreads();
#pragma unroll
    for (int kk = 0; kk < 16; ++kk) {
      float4 a0 = *(const float4*)&As[kk][tm];
      float4 a1 = *(const float4*)&As[kk][tm + 4];
      float4 b0 = *(const float4*)&Bs[kk][tn];
      float av[8] = {a0.x, a0.y, a0.z, a0.w, a1.x, a1.y, a1.z, a1.w};
      float bv[4] = {b0.x, b0.y, b0.z, b0.w};
#pragma unroll
      for (int i = 0; i < 8; ++i)
#pragma unroll
        for (int j = 0; j < 4; ++j) acc[i][j] += av[i] * bv[j];
    }
    __syncthreads();
  }
#pragma unroll
  for (int i = 0; i < 8; ++i)
#pragma unroll
    for (int j = 0; j < 4; ++j) {
      float v = acc[i][j];
      if (bias) v += bias[bn + tn + j];
      if (act == 1) v = fmaxf(v, 0.f);
      C[(size_t)(bm + tm + i) * N + bn + tn + j] = v;
    }
}

__global__ void k_pm_transpose(Args a) {
  int i = blockIdx.x * blockDim.x + threadIdx.x;  // dest (b*128+q)*256 + l
  if (i >= BB * 128 * LL) return;
  int l = i & 255;
  int rest = i >> 8;
  int q = rest & 127, b = rest >> 7;
  a.pm2[i] = a.X[(size_t)((b << 8) + l) * 128 + q];
}

__global__ void k_addspkq(Args a) {
  int i = blockIdx.x * blockDim.x + threadIdx.x;
  if (i >= TT * BB * 128) return;
  int q = i & 127, b = (i >> 7) & 15;
  a.qp2[i] += a.spkq[b * 128 + q];
}

// ================= persistent decoder loop =================
// iter t: attn(t) || R(t-1) || LSTM1(t-2) || LSTM2(t-3); 259 iterations.
__global__ __launch_bounds__(256, 1) void k_persist(Args a) {
  __shared__ __align__(16) float xs[16 * P1];   // 147,456 B: x staging + reduce
  __shared__ __align__(16) float asc[720];      // attn: loc0|loc1|F(16x36)|expv
  __shared__ __align__(16) float gbuf2[280];    // gate exchange [4][68]
  const int wg = blockIdx.x, tid = threadIdx.x;
  const int wv = tid >> 6, lane = tid & 63;
  const int d0 = wg * 4, kl = lane * 4;
  const int ag = tid & 15, ll = tid >> 4;

  float* loc0 = asc;
  float* loc1 = asc + 64;
  float* aF   = asc + 128;   // 16 x 36 (pitch 36: 16B-aligned rows, 2-way banks)
  float* expv = asc + 704;   // 16

  // ---- stationary LSTM weights (loaded once) ----
  float4 wL1[9][4];
  float4 wL2[8][4];
#pragma unroll
  for (int q = 0; q < 4; ++q) {
    const int row = wv * 1024 + d0 + q;
    const float* rih1 = a.Wih1 + (size_t)row * 1280;
    const float* rhh1 = a.Whh1 + (size_t)row * 1024;
    const float* rih2 = a.Wih2 + (size_t)row * 1024;
    const float* rhh2 = a.Whh2 + (size_t)row * 1024;
#pragma unroll
    for (int kb = 0; kb < 9; ++kb)
      wL1[kb][q] = (kb < 5) ? *(const float4*)(rih1 + kb * 256 + kl)
                            : *(const float4*)(rhh1 + kb * 256 + kl - 1280);
#pragma unroll
    for (int kb = 0; kb < 8; ++kb)
      wL2[kb][q] = (kb < 4) ? *(const float4*)(rih2 + kb * 256 + kl)
                            : *(const float4*)(rhh2 + kb * 256 + kl - 1024);
  }
  const int row_r = wv * 1024 + d0 + (lane >> 4);
  const float bsum1 = a.bih1[row_r] + a.bhh1[row_r];
  const float bsum2 = a.bih2[row_r] + a.bhh2[row_r];

  // ---- t-invariant attention operands -> registers ----
  const int bH = wg >> 4, cH = wg & 15, l0H = cH << 4, lH = l0H + ll;
  float pmv[8], va[8];
  {
    const float* pmb = a.pm2 + (size_t)bH * 32768;
#pragma unroll
    for (int j = 0; j < 8; ++j) {
      pmv[j] = pmb[(size_t)(ag * 8 + j) * 256 + lH];
      va[j] = a.vatt[ag * 8 + j];
    }
  }
  float ev[16];
  {
    const float* eb = a.enc + (size_t)((bH << 8) + l0H) * 256 + tid;
#pragma unroll
    for (int l2 = 0; l2 < 16; ++l2) ev[l2] = eb[l2 * 256];
  }

  // LSTM cell state in registers: tid<64 owns (b=tid&15, d=d0+(tid>>4))
  float c1v = 0.f, c2v = 0.f;
  __syncthreads();

  for (int t = 0; t < 259; ++t) {
    const int cur = t & 1, prv = cur ^ 1;

    // ---------- R(s = t-1): reduce pctx -> normalized uctx ----------
    // pctx is 2-parity -> sc0sc1 register loads; psum rotated -> plain L2 hit.
    // Self-draining clds run BEFORE staging issue, so vmcnt(0) is harmless.
    if (wg < 16 && t >= 1 && t <= 256) {
      const int par = (t - 1) & 1, b = wg;
      float sm;
      {
        const f32x4* ps4 = (const f32x4*)(a.psumd + (size_t)(t & 31) * 256 + b * 16);
        f32x4 p0 = ps4[0], p1 = ps4[1], p2 = ps4[2], p3 = ps4[3];
        sm = (p0[0] + p0[1] + p0[2] + p0[3]) + (p1[0] + p1[1] + p1[2] + p1[3]) +
             (p2[0] + p2[1] + p2[2] + p2[3]) + (p3[0] + p3[1] + p3[2] + p3[3]);
      }
      const float inv = 1.f / sm;
      const float* pc = a.pctx + par * 65536 + b * 4096 + tid;
      float d[8];
      float acc = 0.f;
      cld8d(d, pc, pc + 256, pc + 512, pc + 768, pc + 1024, pc + 1280, pc + 1536,
            pc + 1792);
#pragma unroll
      for (int i = 0; i < 8; ++i) acc += d[i];
      cld8d(d, pc + 2048, pc + 2304, pc + 2560, pc + 2816, pc + 3072, pc + 3328,
            pc + 3584, pc + 3840);
#pragma unroll
      for (int i = 0; i < 8; ++i) acc += d[i];
      // uctx(t-1) -> rotated slot t&31
      cst1(a.uctxd + (size_t)(t & 31) * 4096 + b * 256 + tid, acc * inv);
    }

    // ---------- attention(t), part A: all global consumes happen HERE ---------
    float qpm[8], wf[8];
    if (t < 256) {
      float sm;
      {  // psum(t-1): rotated slot t&31, plain (L2-shared, fresh by rotation)
        const f32x4* ps4 = (const f32x4*)(a.psumd + (size_t)(t & 31) * 256 + bH * 16);
        f32x4 p0 = ps4[0], p1 = ps4[1], p2 = ps4[2], p3 = ps4[3];
        sm = (p0[0] + p0[1] + p0[2] + p0[3]) + (p1[0] + p1[1] + p1[2] + p1[3]) +
             (p2[0] + p2[1] + p2[2] + p2[3]) + (p3[0] + p3[1] + p3[2] + p3[3]);
      }
      const float inv_ps = 1.f / sm;
      {
        const float* qpb = a.qp2 + ((size_t)(t << 4) + bH) * 128 + ag * 8;
        float4 q0 = *(const float4*)qpb;
        float4 q1 = *(const float4*)(qpb + 4);
        qpm[0] = q0.x + pmv[0]; qpm[1] = q0.y + pmv[1];
        qpm[2] = q0.z + pmv[2]; qpm[3] = q0.w + pmv[3];
        qpm[4] = q1.x + pmv[4]; qpm[5] = q1.y + pmv[5];
        qpm[6] = q1.z + pmv[6]; qpm[7] = q1.w + pmv[7];
      }
      if (tid < 64) {
        int lp = l0H - 16 + tid;
        bool ok = (lp >= 0 && lp < LL);
        float we = 0.f, cm = 0.f;
        if (ok)  // wexp/cum: 2-parity -> sc0sc1 (one batched RT)
          cld2(&we, &cm, a.wexp + prv * 4096 + bH * 256 + lp,
               a.cum + prv * 4096 + bH * 256 + lp);
        float wn = we * inv_ps;
        loc0[tid] = wn;
        loc1[tid] = ok ? (cm + wn) : 0.f;
      }
      bar_lgkm();
      // cum(t) own slice = cumulative through step t-1
      if (tid < 16) cst1(a.cum + cur * 4096 + bH * 256 + l0H + tid, loc1[16 + tid]);
      for (int idx = tid; idx < FILTD * 16; idx += 256) {
        int fc = idx >> 4, ll2 = idx & 15;
        const float* w = a.Wconv + fc * 62;
        float s = 0.f;
#pragma unroll
        for (int k = 0; k < KC; ++k) {
          s += w[k] * loc0[ll2 + k + 1];
          s += w[31 + k] * loc1[ll2 + k + 1];
        }
        aF[ll2 * 36 + fc] = s;
      }
      bar_lgkm();
      // wf[j] = (Wloc @ F)[r][ll], r=ag*8+j — same thread produces & consumes.
      {
        const float* ftr = aF + ll * 36;
        f32x4 f[8];
#pragma unroll
        for (int c4 = 0; c4 < 8; ++c4) f[c4] = *(const f32x4*)(ftr + c4 * 4);
#pragma unroll
        for (int j = 0; j < 8; ++j) {
          const float* wl = a.Wloc + (ag * 8 + j) * 32;
          float x = 0.f;
#pragma unroll
          for (int c4 = 0; c4 < 8; ++c4) {
            float4 w4 = *(const float4*)(wl + c4 * 4);
            x += w4.x * f[c4][0] + w4.y * f[c4][1] + w4.z * f[c4][2] + w4.w * f[c4][3];
          }
          wf[j] = x;
        }
      }
    }

    // ---------- LSTM1(t-2) staging: async L2-cached glls, rotated srcs -------
    if (t >= 2 && t <= 257) {
      const int s1 = t - 2;
      const float* pt = a.p + (size_t)s1 * 16384;
      const float* h1r = a.h1d + (size_t)(s1 & 31) * 16384;          // h1(s1-1)
      const float* uc = a.uctxd + (size_t)((s1 + 1) & 31) * 4096;    // uctx(s1)
#pragma unroll
      for (int k = 0; k < 16; ++k)
        glls(pt + (size_t)(tid + k * 256) * 4, xs + k * P1 + wv * 256);
#pragma unroll
      for (int k = 0; k < 4; ++k)
        glls(uc + (size_t)(tid + k * 256) * 4, xs + (k * 4 + wv) * P1 + 1024);
#pragma unroll
      for (int k = 0; k < 16; ++k)
        glls(h1r + (size_t)(tid + k * 256) * 4, xs + k * P1 + 1280 + wv * 256);
    }

    // ---------- attention(t), part B: LOAD-FREE (regs + LDS only) ------------
    if (t < 256) {
      {
        float s = 0.f;
#pragma unroll
        for (int j = 0; j < 8; ++j) s += va[j] * fast_tanh(qpm[j] + wf[j]);
        s += __shfl_down(s, 8, 16);
        s += __shfl_down(s, 4, 16);
        s += __shfl_down(s, 2, 16);
        s += __shfl_down(s, 1, 16);
        if (ag == 0) {
          float ex = __expf(s);  // |e| small -> no max-subtraction needed
          expv[ll] = ex;
          cst1(a.wexp + cur * 4096 + bH * 256 + lH, ex);
        }
      }
      bar_lgkm();  // expv visible; staging stays in flight
      if (tid == 0) {
        float s = 0.f;
#pragma unroll
        for (int i = 0; i < 16; ++i) s += expv[i];
        // psum(t) -> rotated slot (t+1)&31
        cst1(a.psumd + (size_t)((t + 1) & 31) * 256 + bH * 16 + cH, s);
      }
      {
        float sctx = 0.f;
#pragma unroll
        for (int l2 = 0; l2 < 16; ++l2) sctx += expv[l2] * ev[l2];
        cst1(a.pctx + cur * 65536 + (bH * 16 + cH) * 256 + tid, sctx);
      }
    }

    // ---------- LSTM1(t-2) compute ----------
    if (t >= 2 && t <= 257) {
      __syncthreads();  // drains vmcnt(0): staging arrived, xs visible
      float acc[4][16];
#pragma unroll
      for (int q = 0; q < 4; ++q)
#pragma unroll
        for (int b = 0; b < 16; ++b) acc[q][b] = 0.f;
#pragma unroll
      for (int kb = 0; kb < 9; ++kb) {
        const float* xb = xs + kb * 256 + kl;
#pragma unroll
        for (int b = 0; b < 16; ++b) {
          float4 x4 = *(const float4*)(xb + b * P1);
#pragma unroll
          for (int q = 0; q < 4; ++q) {
            acc[q][b] += wL1[kb][q].x * x4.x;
            acc[q][b] += wL1[kb][q].y * x4.y;
            acc[q][b] += wL1[kb][q].z * x4.z;
            acc[q][b] += wL1[kb][q].w * x4.w;
          }
        }
      }
      // collapse 64 -> 16 lane-columns
#pragma unroll
      for (int q = 0; q < 4; ++q)
#pragma unroll
        for (int b = 0; b < 16; ++b) {
          float v = acc[q][b];
          v += __shfl_xor(v, 32);
          v += __shfl_xor(v, 16);
          acc[q][b] = v;
        }
      bar_lgkm();  // REDOFF overlaps x rows 14/15 — all reads complete first
      if (lane < 16) {
        float* rb = xs + REDOFF + wv * 1024 + lane * 64;
        const int sx = lane << 2;
#pragma unroll
        for (int q = 0; q < 4; ++q)
#pragma unroll
          for (int bg = 0; bg < 4; ++bg) {
            f32x4 v = {acc[q][bg * 4 + 0], acc[q][bg * 4 + 1],
                       acc[q][bg * 4 + 2], acc[q][bg * 4 + 3]};
            *(f32x4*)(rb + ((q * 16 + bg * 4) ^ sx)) = v;
          }
      }
    }

    // ---------- LSTM2(t-3) staging: async L2-cached glls, rotated srcs -------
    // xs[0..32768) is free (barrier above); REDOFF region disjoint.
    if (t >= 3) {
      const int s2 = t - 3;
      const float* h1s = a.h1d + (size_t)((s2 + 1) & 31) * 16384;  // h1(s2)
      const float* h2r = a.h2d + (size_t)(s2 & 31) * 16384;        // h2(s2-1)
#pragma unroll
      for (int k = 0; k < 16; ++k)
        glls(h1s + (size_t)(tid + k * 256) * 4, xs + k * P2 + wv * 256);
#pragma unroll
      for (int k = 0; k < 16; ++k)
        glls(h2r + (size_t)(tid + k * 256) * 4, xs + k * P2 + 1024 + wv * 256);
    }

    // ---------- LSTM1(t-2) finish: readback (wave-local) + gates ----------
    if (t >= 2 && t <= 257) {
      const int s1 = t - 2;
      float* h1w = a.h1d + (size_t)((s1 + 1) & 31) * 16384;  // h1(s1)
      {
        const int lo = lane & ~3, li = lane & 3;
        const float* rbase = xs + REDOFF + wv * 1024;
        float g = bsum1;
#pragma unroll
        for (int k = 0; k < 16; ++k) g += rbase[k * 64 + (lo ^ (k << 2)) + li];
        gbuf2[wv * 68 + lane] = g;  // (gate=wv, d=d0+(lane>>4), b=lane&15)
      }
      bar_lgkm();
      if (tid < 64) {
        int dd = tid >> 4, b = tid & 15, d = d0 + dd;
        float gi = gbuf2[0 * 68 + tid], gf = gbuf2[1 * 68 + tid];
        float gg = gbuf2[2 * 68 + tid], go = gbuf2[3 * 68 + tid];
        float cn = fast_sig(gf) * c1v + fast_sig(gi) * fast_tanh(gg);
        float hn = fast_sig(go) * fast_tanh(cn);
        c1v = cn;
        cst1(h1w + b * 1024 + d, hn);  // cross-WG: write-through
      }
    }

    // ---------- LSTM2(t-3) compute + finish ----------
    if (t >= 3) {
      const int s2 = t - 3;
      float* h2w = a.h2d + (size_t)((s2 + 1) & 31) * 16384;  // h2(s2)
      __syncthreads();  // drains vmcnt(0): LSTM2 staging arrived
      float acc[4][16];
#pragma unroll
      for (int q = 0; q < 4; ++q)
#pragma unroll
        for (int b = 0; b < 16; ++b) acc[q][b] = 0.f;
#pragma unroll
      for (int kb = 0; kb < 8; ++kb) {
        const float* xb = xs + kb * 256 + kl;
#pragma unroll
        for (int b = 0; b < 16; ++b) {
          float4 x4 = *(const float4*)(xb + b * P2);
#pragma unroll
          for (int q = 0; q < 4; ++q) {
            acc[q][b] += wL2[kb][q].x * x4.x;
            acc[q][b] += wL2[kb][q].y * x4.y;
            acc[q][b] += wL2[kb][q].z * x4.z;
            acc[q][b] += wL2[kb][q].w * x4.w;
          }
        }
      }
#pragma unroll
      for (int q = 0; q < 4; ++q)
#pragma unroll
        for (int b = 0; b < 16; ++b) {
          float v = acc[q][b];
          v += __shfl_xor(v, 32);
          v += __shfl_xor(v, 16);
          acc[q][b] = v;
        }
      // REDOFF [32768,36864) disjoint from LSTM2 x rows [0,32768) — no barrier
      if (lane < 16) {
        float* rb = xs + REDOFF + wv * 1024 + lane * 64;
        const int sx = lane << 2;
#pragma unroll
        for (int q = 0; q < 4; ++q)
#pragma unroll
          for (int bg = 0; bg < 4; ++bg) {
            f32x4 v = {acc[q][bg * 4 + 0], acc[q][bg * 4 + 1],
                       acc[q][bg * 4 + 2], acc[q][bg * 4 + 3]};
            *(f32x4*)(rb + ((q * 16 + bg * 4) ^ sx)) = v;
          }
      }
      {
        const int lo = lane & ~3, li = lane & 3;
        const float* rbase = xs + REDOFF + wv * 1024;
        float g = bsum2;
#pragma unroll
        for (int k = 0; k < 16; ++k) g += rbase[k * 64 + (lo ^ (k << 2)) + li];
        gbuf2[wv * 68 + lane] = g;
      }
      bar_lgkm();
      if (tid < 64) {
        int dd = tid >> 4, b = tid & 15, d = d0 + dd;
        float gi = gbuf2[0 * 68 + tid], gf = gbuf2[1 * 68 + tid];
        float gg = gbuf2[2 * 68 + tid], go = gbuf2[3 * 68 + tid];
        float cn = fast_sig(gf) * c2v + fast_sig(gi) * fast_tanh(gg);
        float hn = fast_sig(go) * fast_tanh(cn);
        c2v = cn;
        cst1(h2w + b * 1024 + d, hn);                // cross-WG: coherent
        a.X[(size_t)(s2 * 16 + b) * 1024 + d] = hn;  // epilogue-only: plain
      }
    }

    if (t < 258) gridbar(a.slots, a.epoch, t + 1, (t & 15) == 15);
  }
}

__global__ void k_finish(Args a) {
  int i = blockIdx.x * blockDim.x + threadIdx.x;  // tb*128+col
  if (i >= 4096 * 128) return;
  int col = i & 127, tb = i >> 7;
  int t = tb >> 4, b = tb & 15;
  float v = a.tmp[i];
  if (col < 80) a.out[(size_t)(b * 256 + t) * 80 + col] = v;
  else if (col == 80) a.out[327680 + b * 256 + t] = fast_sig(v);
}

}  // namespace

extern "C" void kernel_launch(void* const* d_in, const int* in_sizes, int n_in,
                              void* d_out, int out_size, void* d_ws, size_t ws_size,
                              hipStream_t stream) {
  float* ws = (float*)d_ws;
  Args a;
  a.enc = (const float*)d_in[0];
  a.spe = (const float*)d_in[1];
  a.mels = (const float*)d_in[2];
  a.Wpre1 = (const float*)d_in[3];  a.bpre1 = (const float*)d_in[4];
  a.Wpre2 = (const float*)d_in[5];  a.bpre2 = (const float*)d_in[6];
  a.Wsp = (const float*)d_in[7];    a.bsp = (const float*)d_in[8];
  a.Wq = (const float*)d_in[9];     a.Wm = (const float*)d_in[10];
  a.Wconv = (const float*)d_in[11]; a.Wloc = (const float*)d_in[12];
  a.vatt = (const float*)d_in[13];
  a.Wih1 = (const float*)d_in[14];  a.Whh1 = (const float*)d_in[15];
  a.bih1 = (const float*)d_in[16];  a.bhh1 = (const float*)d_in[17];
  a.Wih2 = (const float*)d_in[18];  a.Whh2 = (const float*)d_in[19];
  a.bih2 = (const float*)d_in[20];  a.bhh2 = (const float*)d_in[21];
  a.Wmel = (const float*)d_in[22];  a.bmel = (const float*)d_in[23];
  a.Wstop = (const float*)d_in[24]; a.bstop = (const float*)d_in[25];

  // ws layout (floats), total 11,569,856 floats ~= 46.3 MB
  a.p    = ws + 0;         // 4096x1024
  a.X    = ws + 4194304;   // prenet hidden -> pm temp -> h2_all
  a.qp2  = ws + 8388608;   // 4096x128
  a.pm2  = ws + 8912896;   // 16x128x256
  float* st = ws + 9437184;  // STATE block, 270,912 floats (zeroed each launch)
  a.cum  = st + 98304;    // [2][16][256]
  a.wexp = st + 106496;   // [2][16][256]
  a.pctx = st + 122880;   // [2][16][16][256]
  a.slots  = (int*)(st + 254464);  // 256 slots x 32-int pad
  a.epoch  = (int*)(st + 262656);  // 1 x 32-int pad
  a.spkvec = ws + 9708096;  // 16x1024
  a.spkq   = ws + 9724480;  // 16x128
  a.W81    = ws + 9726528;  // 128x1024 (rows 81..127 unused)
  a.b81    = ws + 9857600;  // 128
  a.tmp    = ws + 9857728;  // 4096x128 -> ends 10,382,016
  a.prevmel = a.tmp;        // prologue-only, aliases epilogue tmp
  // depth-32 rotating broadcast buffers (slot = (step+1)&31)
  a.h1d   = ws + 10382016;  // 32 x 16384 (2 MB)
  a.h2d   = ws + 10906304;  // 32 x 16384 (2 MB)
  a.uctxd = ws + 11430592;  // 32 x 4096  (0.5 MB)
  a.psumd = ws + 11561664;  // 32 x 256   (32 KB) -> ends 11,569,856
  a.out = (float*)d_out;

  k_init<<<(270912 + 255) / 256, 256, 0, stream>>>(st, 270912);
  k_init<<<64, 256, 0, stream>>>(a.h1d, 16384);    // h1(-1) = slot 0
  k_init<<<64, 256, 0, stream>>>(a.h2d, 16384);    // h2(-1) = slot 0
  k_init<<<1, 256, 0, stream>>>(a.psumd, 256);     // psum(-1) = slot 0
  k_setpsum<<<1, 64, 0, stream>>>(a.psumd);
  k_prevmel<<<(TT * BB * MELD + 255) / 256, 256, 0, stream>>>(a);
  k_spkvec<<<(BB * 1024 + 255) / 256, 256, 0, stream>>>(a);
  k_spkq<<<(BB * 128 + 255) / 256, 256, 0, stream>>>(a);
  k_prep81<<<(81 * 1024 + 255) / 256, 256, 0, stream>>>(a);

  // prenet1 -> X (temp), prenet2 -> p
  k_gemm<<<dim3(16, 32), 256, 0, stream>>>(a.prevmel, a.Wpre1, a.bpre1, a.X, 4096, 1024, 80, 1);
  k_gemm<<<dim3(16, 32), 256, 0, stream>>>(a.X, a.Wpre2, a.bpre2, a.p, 4096, 1024, 1024, 1);
  // qp2 = p @ Wq^T (+ spk @ Wq^T)
  k_gemm<<<dim3(2, 32), 256, 0, stream>>>(a.p, a.Wq, nullptr, a.qp2, 4096, 128, 1024, 0);
  k_addspkq<<<(TT * BB * 128 + 255) / 256, 256, 0, stream>>>(a);
  // proc_mem = enc @ Wm^T -> X temp -> transpose to [b][att][l]
  k_gemm<<<dim3(2, 32), 256, 0, stream>>>(a.enc, a.Wm, nullptr, a.X, 4096, 128, 256, 0);
  k_pm_transpose<<<(BB * 128 * LL + 255) / 256, 256, 0, stream>>>(a);

  // persistent decoder: 256 WGs (1/CU), cooperative; fallback to plain launch
  {
    void* kargs[] = {(void*)&a};
    hipError_t e = hipLaunchCooperativeKernel(reinterpret_cast<const void*>(&k_persist),
                                              dim3(256), dim3(256), kargs, 0, stream);
    if (e != hipSuccess) k_persist<<<256, 256, 0, stream>>>(a);
  }

  // mel/stop projection: h2_all @ W81^T -> tmp, then scatter
  k_gemm<<<dim3(2, 32), 256, 0, stream>>>(a.X, a.W81, a.b81, a.tmp, 4096, 128, 1024, 0);
  k_finish<<<(4096 * 128 + 255) / 256, 256, 0, stream>>>(a);
}